// Round 1
// baseline (87.761 us; speedup 1.0000x reference)
//
#include <hip/hip_runtime.h>
#include <hip/hip_bf16.h>
#include <stdint.h>

// Problem constants: B=2, L=2048, E=1024, H=16, HD=64, G=4.
#define L_SEQ 2048
#define MTOT  4096   // B*L
#define EDIM  1024

typedef __attribute__((ext_vector_type(8))) short bf16x8;   // 8 bf16 (4 VGPRs)
typedef __attribute__((ext_vector_type(4))) float f32x4;
typedef __attribute__((ext_vector_type(4))) float float4v;
typedef __attribute__((ext_vector_type(4))) unsigned short us4;
typedef __attribute__((ext_vector_type(2))) unsigned int u32x2;

__device__ __forceinline__ unsigned short f2b(float f) {
    union { float f; unsigned u; } v; v.f = f;
    return (unsigned short)((v.u + 0x7FFFu + ((v.u >> 16) & 1u)) >> 16);  // RNE
}
__device__ __forceinline__ float b2f(unsigned short h) {
    union { unsigned u; float f; } v; v.u = ((unsigned)h) << 16;
    return v.f;
}

__device__ __forceinline__ void lds16(const void* g, void* l) {
    __builtin_amdgcn_global_load_lds((const __attribute__((address_space(1))) void*)g,
                                     (__attribute__((address_space(3))) void*)l, 16, 0, 0);
}

// ---------------------------------------------------------------------------
// prep: convert x -> bf16; stitch W1 = [Wv rows 0..255 ; Wq rows 256..1023] -> bf16;
//       convert Wo -> bf16. One element-range kernel, float4 in / ushort4 out.
// ---------------------------------------------------------------------------
__global__ __launch_bounds__(256) void prep_kernel(
    const float* __restrict__ x, const float* __restrict__ Wq,
    const float* __restrict__ Wv, const float* __restrict__ Wo,
    unsigned short* __restrict__ xb, unsigned short* __restrict__ W1b,
    unsigned short* __restrict__ Wob)
{
    const int XQ = (MTOT * EDIM) / 4;   // 1,048,576 quads
    const int WQ = (EDIM * EDIM) / 4;   //   262,144 quads
    int i = blockIdx.x * 256 + threadIdx.x;
    const float* src;
    unsigned short* dst;
    int j;
    if (i < XQ) {
        j = i * 4; src = x; dst = xb;
    } else if (i < XQ + WQ) {
        j = (i - XQ) * 4;
        int row = j >> 10;                 // /1024
        src = (row < 256) ? Wv : Wq;       // stitched W1
        dst = W1b;
    } else {
        j = (i - XQ - WQ) * 4; src = Wo; dst = Wob;
    }
    float4v v = *(const float4v*)(src + j);
    us4 o;
    o[0] = f2b(v[0]); o[1] = f2b(v[1]); o[2] = f2b(v[2]); o[3] = f2b(v[3]);
    *(us4*)(dst + j) = o;
}

// ---------------------------------------------------------------------------
// taps: compose the two causal depthwise convs into one FIR per channel.
//   dwconv: y[l] = b + sum_j w[:,j] * x[l-(k-1)+j]  ==> taps h[i] = w[k-1-i].
//   chain (v o q): h = hq (*) hv (len 2k-1<=13), beff = vb + qb*sum_j(vw).
//   boundary: for l<k-1 the reference zero-pads the INTERMEDIATE, so the qb
//   term only enters for taps i<=l -> Corr[l][ch] = qb*sum_{i=l+1..}(hv[i]).
// Channels ch in [0,768): group g=ch>>8 (k=3,5,7), within-head d=ch&63.
// H layout [13][768], Corr [6][768] (coalesced loads per tap in conv kernel).
// ---------------------------------------------------------------------------
__global__ void taps_kernel(
    const float* __restrict__ q3w, const float* __restrict__ q3b,
    const float* __restrict__ v3w, const float* __restrict__ v3b,
    const float* __restrict__ q5w, const float* __restrict__ q5b,
    const float* __restrict__ v5w, const float* __restrict__ v5b,
    const float* __restrict__ q7w, const float* __restrict__ q7b,
    const float* __restrict__ v7w, const float* __restrict__ v7b,
    float* __restrict__ H, float* __restrict__ Beff, float* __restrict__ Corr)
{
    int ch = blockIdx.x * 64 + threadIdx.x;
    if (ch >= 768) return;
    int g = ch >> 8;          // 0,1,2 -> ksz 3,5,7
    int d = ch & 63;
    int k = 3 + 2 * g;
    const float* qw = (g == 0) ? q3w : (g == 1) ? q5w : q7w;
    const float* qb = (g == 0) ? q3b : (g == 1) ? q5b : q7b;
    const float* vw = (g == 0) ? v3w : (g == 1) ? v5w : v7w;
    const float* vb = (g == 0) ? v3b : (g == 1) ? v5b : v7b;

    float hq[7], hv[7];
    for (int i = 0; i < 7; ++i) { hq[i] = 0.f; hv[i] = 0.f; }
    for (int i = 0; i < k; ++i) {
        hq[i] = qw[d * k + (k - 1 - i)];
        hv[i] = vw[d * k + (k - 1 - i)];
    }
    float h[13];
    for (int i = 0; i < 13; ++i) h[i] = 0.f;
    for (int a = 0; a < 7; ++a)
        for (int b = 0; b < 7; ++b)
            h[a + b] += hq[a] * hv[b];
    for (int i = 0; i < 13; ++i) H[i * 768 + ch] = h[i];

    float sv = 0.f;
    for (int j = 0; j < k; ++j) sv += vw[d * k + j];
    Beff[ch] = qb[d] * sv + vb[d];

    for (int l = 0; l < 6; ++l) {
        float s2 = 0.f;
        for (int i = l + 1; i < 7; ++i) s2 += hv[i];
        Corr[l * 768 + ch] = qb[d] * s2;
    }
}

// ---------------------------------------------------------------------------
// GEMM: C[M,N] = A[M,K] * BT[N,K]^T   (m97 structure: 128x128 tile, BK=32,
// 4 waves 2x2, each wave 64x64 = 4x4 frags of mfma_f32_16x16x32_bf16,
// global_load_lds width 16 staging, linear LDS).
// OUT_MODE 0: bf16 store. OUT_MODE 1: f32 store + bias[col].
// ---------------------------------------------------------------------------
template <int OUT_MODE>
__global__ __launch_bounds__(256) void gemm_bt(
    const unsigned short* __restrict__ A, const unsigned short* __restrict__ BT,
    unsigned short* __restrict__ Cb, float* __restrict__ Cf,
    const float* __restrict__ bias, int M, int N, int K)
{
    __shared__ unsigned short As[128 * 32];
    __shared__ unsigned short Bs[128 * 32];

    const int tid  = threadIdx.x;
    const int wid  = tid >> 6;
    const int lane = tid & 63;
    const int wr   = wid >> 1, wc = wid & 1;          // 2x2 wave grid, 64x64 each
    const int m0   = blockIdx.y * 128, n0 = blockIdx.x * 128;

    f32x4 acc[4][4] = {};

    const int srow = lane >> 2;          // staging row within 16-row chunk
    const int scol = (lane & 3) * 8;     // staging col (elements)
    const int j0 = wid, j1 = wid + 4;    // 1KB LDS chunks owned by this wave

    const unsigned short* Abase = A  + (size_t)m0 * K;
    const unsigned short* Bbase = BT + (size_t)n0 * K;

    const int fr = lane & 15, fq = lane >> 4;

    for (int k0 = 0; k0 < K; k0 += 32) {
        lds16(Abase + (size_t)(j0 * 16 + srow) * K + k0 + scol, As + j0 * 512);
        lds16(Abase + (size_t)(j1 * 16 + srow) * K + k0 + scol, As + j1 * 512);
        lds16(Bbase + (size_t)(j0 * 16 + srow) * K + k0 + scol, Bs + j0 * 512);
        lds16(Bbase + (size_t)(j1 * 16 + srow) * K + k0 + scol, Bs + j1 * 512);
        __syncthreads();   // compiler drains vmcnt before barrier

        bf16x8 a[4], b[4];
#pragma unroll
        for (int mi = 0; mi < 4; ++mi)
            a[mi] = *(const bf16x8*)(As + (wr * 64 + mi * 16 + fr) * 32 + fq * 8);
#pragma unroll
        for (int ni = 0; ni < 4; ++ni)
            b[ni] = *(const bf16x8*)(Bs + (wc * 64 + ni * 16 + fr) * 32 + fq * 8);
#pragma unroll
        for (int mi = 0; mi < 4; ++mi)
#pragma unroll
            for (int ni = 0; ni < 4; ++ni)
                acc[mi][ni] = __builtin_amdgcn_mfma_f32_16x16x32_bf16(a[mi], b[ni], acc[mi][ni], 0, 0, 0);
        __syncthreads();
    }

    // epilogue: C/D layout col=lane&15, row=(lane>>4)*4+j  [m89-verified]
#pragma unroll
    for (int mi = 0; mi < 4; ++mi) {
#pragma unroll
        for (int ni = 0; ni < 4; ++ni) {
            int col  = n0 + wc * 64 + ni * 16 + fr;
            int rowb = m0 + wr * 64 + mi * 16 + fq * 4;
#pragma unroll
            for (int j = 0; j < 4; ++j) {
                float v = acc[mi][ni][j];
                if (OUT_MODE == 0) {
                    Cb[(size_t)(rowb + j) * N + col] = f2b(v);
                } else {
                    Cf[(size_t)(rowb + j) * N + col] = v + bias[col];
                }
            }
        }
    }
}

// ---------------------------------------------------------------------------
// conv: V[m][e] = T[m][e] for e<256 (pass-through v0);
//       else FIR over l (within batch) with combined taps + boundary corr.
// Thread handles 4 channels at one position m. T is L2-resident (8MB).
// ---------------------------------------------------------------------------
__global__ __launch_bounds__(256) void conv_kernel(
    const unsigned short* __restrict__ T, unsigned short* __restrict__ V,
    const float* __restrict__ H, const float* __restrict__ Beff,
    const float* __restrict__ Corr)
{
    int w  = blockIdx.x * 256 + threadIdx.x;   // 4096*256 work items
    int m  = w >> 8;
    int c4 = w & 255;
    int e0 = c4 * 4;
    const unsigned short* tp = T + (size_t)m * EDIM + e0;
    unsigned short*       vp = V + (size_t)m * EDIM + e0;
    if (e0 < 256) {                       // v0 pass-through
        *(u32x2*)vp = *(const u32x2*)tp;
        return;
    }
    int l  = m & (L_SEQ - 1);
    int ch = e0 - 256;
    float4v acc = *(const float4v*)(Beff + ch);
    int ni = (l < 12) ? l : 12;
    for (int i = 0; i <= ni; ++i) {
        float4v h = *(const float4v*)(H + i * 768 + ch);
        us4 t = *(const us4*)(tp - (size_t)i * EDIM);
        acc[0] += h[0] * b2f(t[0]);
        acc[1] += h[1] * b2f(t[1]);
        acc[2] += h[2] * b2f(t[2]);
        acc[3] += h[3] * b2f(t[3]);
    }
    if (l < 6) {   // bias boundary correction (intermediate zero-padding)
        float4v c = *(const float4v*)(Corr + l * 768 + ch);
        acc[0] -= c[0]; acc[1] -= c[1]; acc[2] -= c[2]; acc[3] -= c[3];
    }
    us4 o;
    o[0] = f2b(acc[0]); o[1] = f2b(acc[1]); o[2] = f2b(acc[2]); o[3] = f2b(acc[3]);
    *(us4*)vp = o;
}

// ---------------------------------------------------------------------------
extern "C" void kernel_launch(void* const* d_in, const int* in_sizes, int n_in,
                              void* d_out, int out_size, void* d_ws, size_t ws_size,
                              hipStream_t stream)
{
    const float* x  = (const float*)d_in[0];
    const float* Wq = (const float*)d_in[1];
    // d_in[2] = Wk (dead: attention output is multiplied by 0.0)
    const float* Wv = (const float*)d_in[3];
    const float* Wo = (const float*)d_in[4];
    const float* bo = (const float*)d_in[5];

    uint8_t* ws = (uint8_t*)d_ws;
    unsigned short* xb  = (unsigned short*)(ws);                    //  8 MB
    unsigned short* W1b = (unsigned short*)(ws + (8u  << 20));      //  2 MB
    unsigned short* Wob = (unsigned short*)(ws + (10u << 20));      //  2 MB
    unsigned short* T   = (unsigned short*)(ws + (12u << 20));      //  8 MB
    unsigned short* V   = (unsigned short*)(ws + (20u << 20));      //  8 MB
    float* H    = (float*)(ws + (28u << 20));                        // 40 KB
    float* Beff = (float*)(ws + (28u << 20) + (64u << 10));          //  3 KB
    float* Corr = (float*)(ws + (28u << 20) + (96u << 10));          // 18 KB

    prep_kernel<<<6144, 256, 0, stream>>>(x, Wq, Wv, Wo, xb, W1b, Wob);

    taps_kernel<<<12, 64, 0, stream>>>(
        (const float*)d_in[6],  (const float*)d_in[7],
        (const float*)d_in[10], (const float*)d_in[11],
        (const float*)d_in[12], (const float*)d_in[13],
        (const float*)d_in[16], (const float*)d_in[17],
        (const float*)d_in[18], (const float*)d_in[19],
        (const float*)d_in[22], (const float*)d_in[23],
        H, Beff, Corr);

    dim3 gg(EDIM / 128, MTOT / 128);   // (8, 32)
    gemm_bt<0><<<gg, 256, 0, stream>>>(xb, W1b, T, nullptr, nullptr, MTOT, EDIM, EDIM);

    conv_kernel<<<4096, 256, 0, stream>>>(T, V, H, Beff, Corr);

    gemm_bt<1><<<gg, 256, 0, stream>>>(V, Wob, nullptr, (float*)d_out, bo, MTOT, EDIM, EDIM);
}

// Round 2
// 72.492 us; speedup vs baseline: 1.2106x; 1.2106x over previous
//
#include <hip/hip_runtime.h>
#include <hip/hip_bf16.h>
#include <stdint.h>

// Problem constants: B=2, L=2048, E=1024, H=16, HD=64, G=4.
#define L_SEQ 2048
#define MTOT  4096   // B*L
#define EDIM  1024

typedef __attribute__((ext_vector_type(8))) short bf16x8;   // 8 bf16 (4 VGPRs)
typedef __attribute__((ext_vector_type(4))) float f32x4;
typedef __attribute__((ext_vector_type(4))) float float4v;
typedef __attribute__((ext_vector_type(4))) unsigned short us4;
typedef __attribute__((ext_vector_type(2))) unsigned int u32x2;

__device__ __forceinline__ unsigned short f2b(float f) {
    union { float f; unsigned u; } v; v.f = f;
    return (unsigned short)((v.u + 0x7FFFu + ((v.u >> 16) & 1u)) >> 16);  // RNE
}
__device__ __forceinline__ float b2f(unsigned short h) {
    union { unsigned u; float f; } v; v.u = ((unsigned)h) << 16;
    return v.f;
}

__device__ __forceinline__ void lds16(const void* g, void* l) {
    __builtin_amdgcn_global_load_lds((const __attribute__((address_space(1))) void*)g,
                                     (__attribute__((address_space(3))) void*)l, 16, 0, 0);
}

// ---------------------------------------------------------------------------
// prep: convert x -> bf16; stitch W1 = [Wv rows 0..255 ; Wq rows 256..1023];
//       convert Wo -> bf16. float4 in / ushort4 out.
// ---------------------------------------------------------------------------
__global__ __launch_bounds__(256) void prep_kernel(
    const float* __restrict__ x, const float* __restrict__ Wq,
    const float* __restrict__ Wv, const float* __restrict__ Wo,
    unsigned short* __restrict__ xb, unsigned short* __restrict__ W1b,
    unsigned short* __restrict__ Wob)
{
    const int XQ = (MTOT * EDIM) / 4;   // 1,048,576 quads
    const int WQ = (EDIM * EDIM) / 4;   //   262,144 quads
    int i = blockIdx.x * 256 + threadIdx.x;
    const float* src;
    unsigned short* dst;
    int j;
    if (i < XQ) {
        j = i * 4; src = x; dst = xb;
    } else if (i < XQ + WQ) {
        j = (i - XQ) * 4;
        int row = j >> 10;                 // /1024
        src = (row < 256) ? Wv : Wq;       // stitched W1
        dst = W1b;
    } else {
        j = (i - XQ - WQ) * 4; src = Wo; dst = Wob;
    }
    float4v v = *(const float4v*)(src + j);
    us4 o;
    o[0] = f2b(v[0]); o[1] = f2b(v[1]); o[2] = f2b(v[2]); o[3] = f2b(v[3]);
    *(us4*)(dst + j) = o;
}

// ---------------------------------------------------------------------------
// taps: compose the two causal depthwise convs into one FIR per channel.
//   h = hq (*) hv (len 2k-1 <= 13), beff = vb + qb*sum(vw).
//   boundary (l < k-1): intermediate zero-padding drops qb for taps i > l:
//   Corr[l][ch] = qb * sum_{i=l+1..} hv[i].
// ---------------------------------------------------------------------------
__global__ void taps_kernel(
    const float* __restrict__ q3w, const float* __restrict__ q3b,
    const float* __restrict__ v3w, const float* __restrict__ v3b,
    const float* __restrict__ q5w, const float* __restrict__ q5b,
    const float* __restrict__ v5w, const float* __restrict__ v5b,
    const float* __restrict__ q7w, const float* __restrict__ q7b,
    const float* __restrict__ v7w, const float* __restrict__ v7b,
    float* __restrict__ H, float* __restrict__ Beff, float* __restrict__ Corr)
{
    int ch = blockIdx.x * 64 + threadIdx.x;
    if (ch >= 768) return;
    int g = ch >> 8;          // 0,1,2 -> ksz 3,5,7
    int d = ch & 63;
    int k = 3 + 2 * g;
    const float* qw = (g == 0) ? q3w : (g == 1) ? q5w : q7w;
    const float* qb = (g == 0) ? q3b : (g == 1) ? q5b : q7b;
    const float* vw = (g == 0) ? v3w : (g == 1) ? v5w : v7w;
    const float* vb = (g == 0) ? v3b : (g == 1) ? v5b : v7b;

    float hq[7], hv[7];
    for (int i = 0; i < 7; ++i) { hq[i] = 0.f; hv[i] = 0.f; }
    for (int i = 0; i < k; ++i) {
        hq[i] = qw[d * k + (k - 1 - i)];
        hv[i] = vw[d * k + (k - 1 - i)];
    }
    float h[13];
    for (int i = 0; i < 13; ++i) h[i] = 0.f;
    for (int a = 0; a < 7; ++a)
        for (int b = 0; b < 7; ++b)
            h[a + b] += hq[a] * hv[b];
    for (int i = 0; i < 13; ++i) H[i * 768 + ch] = h[i];

    float sv = 0.f;
    for (int j = 0; j < k; ++j) sv += vw[d * k + j];
    Beff[ch] = qb[d] * sv + vb[d];

    for (int l = 0; l < 6; ++l) {
        float s2 = 0.f;
        for (int i = l + 1; i < 7; ++i) s2 += hv[i];
        Corr[l * 768 + ch] = qb[d] * s2;
    }
}

// ---------------------------------------------------------------------------
// GEMM (2-phase double-buffered, T3-minimum): C[M,N] = A[M,K] * BT[N,K]^T
//   BM=128, BN=64, BK=64, 256 threads (4 waves 2x2), wave tile 64x32,
//   acc 4x2 frags of mfma_f32_16x16x32_bf16 (16 MFMA / K-tile / wave).
//   LDS 2*(16K+8K)=48KB. Grid (N/64, M/128) = 512 blocks = 2 blocks/CU.
//   Per iter: issue next-tile global_load_lds FIRST, then ds_read+MFMA on
//   current buffer, then one __syncthreads() (drains vmcnt for next tile
//   and protects the buffer we just read). T2/T5 skipped: null at 2-phase.
// OUT_MODE 0: bf16 store. OUT_MODE 1: f32 store + bias[col].
// ---------------------------------------------------------------------------
template <int OUT_MODE>
__global__ __launch_bounds__(256) void gemm_2ph(
    const unsigned short* __restrict__ A, const unsigned short* __restrict__ BT,
    unsigned short* __restrict__ Cb, float* __restrict__ Cf,
    const float* __restrict__ bias, int M, int N, int K)
{
    __shared__ unsigned short As[2][128 * 64];
    __shared__ unsigned short Bs[2][64 * 64];

    const int tid  = threadIdx.x;
    const int wid  = tid >> 6;
    const int lane = tid & 63;
    const int wr   = wid >> 1, wc = wid & 1;          // 2x2 wave grid
    const int m0   = blockIdx.y * 128, n0 = blockIdx.x * 64;
    const int fr   = lane & 15, fq = lane >> 4;

    f32x4 acc[4][2] = {};

    const unsigned short* Abase = A  + (size_t)m0 * K;
    const unsigned short* Bbase = BT + (size_t)n0 * K;

    // staging: chunk c (16B) of a [R][64] tile lives at LDS offset c*16B,
    // global (row = c>>3, col = (c&7)*8). Per wave-instruction the LDS base
    // is wave-uniform; HW adds lane*16B.
    auto stage = [&](int buf, int k0) {
        const unsigned short* Ab = Abase + k0;
        const unsigned short* Bb = Bbase + k0;
#pragma unroll
        for (int i = 0; i < 4; ++i) {
            int c = wid * 256 + i * 64 + lane;
            lds16(Ab + (size_t)(c >> 3) * K + (c & 7) * 8,
                  &As[buf][(wid * 256 + i * 64) * 8]);
        }
#pragma unroll
        for (int i = 0; i < 2; ++i) {
            int c = wid * 128 + i * 64 + lane;
            lds16(Bb + (size_t)(c >> 3) * K + (c & 7) * 8,
                  &Bs[buf][(wid * 128 + i * 64) * 8]);
        }
    };

    const int NT = K >> 6;   // 16 K-tiles
    stage(0, 0);
    __syncthreads();         // drains vmcnt before barrier
    int cur = 0;

    for (int t = 0; t < NT; ++t) {
        if (t + 1 < NT) stage(cur ^ 1, (t + 1) << 6);   // prefetch next tile
        const unsigned short* as = As[cur];
        const unsigned short* bs = Bs[cur];
#pragma unroll
        for (int s = 0; s < 2; ++s) {                    // two K=32 slabs
            bf16x8 a[4], b[2];
#pragma unroll
            for (int mi = 0; mi < 4; ++mi)
                a[mi] = *(const bf16x8*)(as + (wr * 64 + mi * 16 + fr) * 64 + s * 32 + fq * 8);
#pragma unroll
            for (int ni = 0; ni < 2; ++ni)
                b[ni] = *(const bf16x8*)(bs + (wc * 32 + ni * 16 + fr) * 64 + s * 32 + fq * 8);
#pragma unroll
            for (int mi = 0; mi < 4; ++mi)
#pragma unroll
                for (int ni = 0; ni < 2; ++ni)
                    acc[mi][ni] = __builtin_amdgcn_mfma_f32_16x16x32_bf16(a[mi], b[ni], acc[mi][ni], 0, 0, 0);
        }
        __syncthreads();     // one barrier per K-tile: protects read buffer,
        cur ^= 1;            // and its vmcnt(0) drain completes the prefetch
    }

    // epilogue: C/D layout col=lane&15, row=(lane>>4)*4+j  [m89-verified]
#pragma unroll
    for (int mi = 0; mi < 4; ++mi) {
#pragma unroll
        for (int ni = 0; ni < 2; ++ni) {
            int col  = n0 + wc * 32 + ni * 16 + fr;
            int rowb = m0 + wr * 64 + mi * 16 + fq * 4;
#pragma unroll
            for (int j = 0; j < 4; ++j) {
                float v = acc[mi][ni][j];
                if (OUT_MODE == 0) {
                    Cb[(size_t)(rowb + j) * N + col] = f2b(v);
                } else {
                    Cf[(size_t)(rowb + j) * N + col] = v + bias[col];
                }
            }
        }
    }
}

// ---------------------------------------------------------------------------
// conv: V[m][e] = T[m][e] for e<256 (v0 pass-through);
//       else causal FIR over l with combined taps + boundary corr.
// ---------------------------------------------------------------------------
__global__ __launch_bounds__(256) void conv_kernel(
    const unsigned short* __restrict__ T, unsigned short* __restrict__ V,
    const float* __restrict__ H, const float* __restrict__ Beff,
    const float* __restrict__ Corr)
{
    int w  = blockIdx.x * 256 + threadIdx.x;   // 4096*256 work items
    int m  = w >> 8;
    int c4 = w & 255;
    int e0 = c4 * 4;
    const unsigned short* tp = T + (size_t)m * EDIM + e0;
    unsigned short*       vp = V + (size_t)m * EDIM + e0;
    if (e0 < 256) {                       // v0 pass-through
        *(u32x2*)vp = *(const u32x2*)tp;
        return;
    }
    int l  = m & (L_SEQ - 1);
    int ch = e0 - 256;
    float4v acc = *(const float4v*)(Beff + ch);
    int ni = (l < 12) ? l : 12;
    for (int i = 0; i <= ni; ++i) {
        float4v h = *(const float4v*)(H + i * 768 + ch);
        us4 t = *(const us4*)(tp - (size_t)i * EDIM);
        acc[0] += h[0] * b2f(t[0]);
        acc[1] += h[1] * b2f(t[1]);
        acc[2] += h[2] * b2f(t[2]);
        acc[3] += h[3] * b2f(t[3]);
    }
    if (l < 6) {   // bias boundary correction (intermediate zero-padding)
        float4v c = *(const float4v*)(Corr + l * 768 + ch);
        acc[0] -= c[0]; acc[1] -= c[1]; acc[2] -= c[2]; acc[3] -= c[3];
    }
    us4 o;
    o[0] = f2b(acc[0]); o[1] = f2b(acc[1]); o[2] = f2b(acc[2]); o[3] = f2b(acc[3]);
    *(us4*)vp = o;
}

// ---------------------------------------------------------------------------
extern "C" void kernel_launch(void* const* d_in, const int* in_sizes, int n_in,
                              void* d_out, int out_size, void* d_ws, size_t ws_size,
                              hipStream_t stream)
{
    const float* x  = (const float*)d_in[0];
    const float* Wq = (const float*)d_in[1];
    // d_in[2] = Wk (dead: attention output is multiplied by 0.0)
    const float* Wv = (const float*)d_in[3];
    const float* Wo = (const float*)d_in[4];
    const float* bo = (const float*)d_in[5];

    uint8_t* ws = (uint8_t*)d_ws;
    unsigned short* xb  = (unsigned short*)(ws);                    //  8 MB
    unsigned short* W1b = (unsigned short*)(ws + (8u  << 20));      //  2 MB
    unsigned short* Wob = (unsigned short*)(ws + (10u << 20));      //  2 MB
    unsigned short* T   = (unsigned short*)(ws + (12u << 20));      //  8 MB
    unsigned short* V   = (unsigned short*)(ws + (20u << 20));      //  8 MB
    float* H    = (float*)(ws + (28u << 20));                        // 40 KB
    float* Beff = (float*)(ws + (28u << 20) + (64u << 10));          //  3 KB
    float* Corr = (float*)(ws + (28u << 20) + (96u << 10));          // 18 KB

    prep_kernel<<<6144, 256, 0, stream>>>(x, Wq, Wv, Wo, xb, W1b, Wob);

    taps_kernel<<<12, 64, 0, stream>>>(
        (const float*)d_in[6],  (const float*)d_in[7],
        (const float*)d_in[10], (const float*)d_in[11],
        (const float*)d_in[12], (const float*)d_in[13],
        (const float*)d_in[16], (const float*)d_in[17],
        (const float*)d_in[18], (const float*)d_in[19],
        (const float*)d_in[22], (const float*)d_in[23],
        H, Beff, Corr);

    dim3 gg(EDIM / 64, MTOT / 128);   // (16, 32) = 512 blocks, 2 per CU
    gemm_2ph<0><<<gg, 256, 0, stream>>>(xb, W1b, T, nullptr, nullptr, MTOT, EDIM, EDIM);

    conv_kernel<<<4096, 256, 0, stream>>>(T, V, H, Beff, Corr);

    gemm_2ph<1><<<gg, 256, 0, stream>>>(V, Wob, nullptr, (float*)d_out, bo, MTOT, EDIM, EDIM);
}

// Round 3
// 64.262 us; speedup vs baseline: 1.3657x; 1.1281x over previous
//
#include <hip/hip_runtime.h>
#include <hip/hip_bf16.h>
#include <stdint.h>

// Problem constants: B=2, L=2048, E=1024, H=16, HD=64, G=4.
#define L_SEQ 2048
#define MTOT  4096   // B*L
#define EDIM  1024

typedef __attribute__((ext_vector_type(8))) short bf16x8;   // 8 bf16 (4 VGPRs)
typedef __attribute__((ext_vector_type(4))) float f32x4;
typedef __attribute__((ext_vector_type(4))) float float4v;
typedef __attribute__((ext_vector_type(4))) unsigned short us4;
typedef __attribute__((ext_vector_type(2))) unsigned int u32x2;

__device__ __forceinline__ unsigned short f2b(float f) {
    union { float f; unsigned u; } v; v.f = f;
    return (unsigned short)((v.u + 0x7FFFu + ((v.u >> 16) & 1u)) >> 16);  // RNE
}
__device__ __forceinline__ float b2f(unsigned short h) {
    union { unsigned u; float f; } v; v.u = ((unsigned)h) << 16;
    return v.f;
}

__device__ __forceinline__ void lds16(const void* g, void* l) {
    __builtin_amdgcn_global_load_lds((const __attribute__((address_space(1))) void*)g,
                                     (__attribute__((address_space(3))) void*)l, 16, 0, 0);
}

// ---------------------------------------------------------------------------
// prep: convert x -> bf16; stitch W1 = [Wv rows 0..255 ; Wq rows 256..1023];
//       convert Wo -> bf16. Blocks >= 6144 compute the composed FIR taps.
// ---------------------------------------------------------------------------
__global__ __launch_bounds__(256) void prep_kernel(
    const float* __restrict__ x, const float* __restrict__ Wq,
    const float* __restrict__ Wv, const float* __restrict__ Wo,
    unsigned short* __restrict__ xb, unsigned short* __restrict__ W1b,
    unsigned short* __restrict__ Wob,
    const float* __restrict__ q3w, const float* __restrict__ q3b,
    const float* __restrict__ v3w, const float* __restrict__ v3b,
    const float* __restrict__ q5w, const float* __restrict__ q5b,
    const float* __restrict__ v5w, const float* __restrict__ v5b,
    const float* __restrict__ q7w, const float* __restrict__ q7b,
    const float* __restrict__ v7w, const float* __restrict__ v7b,
    float* __restrict__ H, float* __restrict__ Beff, float* __restrict__ Corr)
{
    const int XQ = (MTOT * EDIM) / 4;   // 1,048,576 quads
    const int WQ = (EDIM * EDIM) / 4;   //   262,144 quads
    if (blockIdx.x >= 6144) {
        // ------- taps: compose the two causal depthwise convs per channel.
        //   dwconv taps h[i] = w[k-1-i]; chain h = hq (*) hv (len 2k-1<=13),
        //   beff = vb + qb*sum(vw); boundary (l<k-1): intermediate zero-pad
        //   drops qb for taps i>l -> Corr[l][ch] = qb*sum_{i=l+1..} hv[i].
        int ch = (blockIdx.x - 6144) * 256 + threadIdx.x;   // [0,768)
        int g = ch >> 8;          // 0,1,2 -> ksz 3,5,7
        int d = ch & 63;
        int k = 3 + 2 * g;
        const float* qw = (g == 0) ? q3w : (g == 1) ? q5w : q7w;
        const float* qb = (g == 0) ? q3b : (g == 1) ? q5b : q7b;
        const float* vw = (g == 0) ? v3w : (g == 1) ? v5w : v7w;
        const float* vb = (g == 0) ? v3b : (g == 1) ? v5b : v7b;

        float hq[7], hv[7];
        for (int i = 0; i < 7; ++i) { hq[i] = 0.f; hv[i] = 0.f; }
        for (int i = 0; i < k; ++i) {
            hq[i] = qw[d * k + (k - 1 - i)];
            hv[i] = vw[d * k + (k - 1 - i)];
        }
        float h[13];
        for (int i = 0; i < 13; ++i) h[i] = 0.f;
        for (int a = 0; a < 7; ++a)
            for (int b = 0; b < 7; ++b)
                h[a + b] += hq[a] * hv[b];
        for (int i = 0; i < 13; ++i) H[i * 768 + ch] = h[i];

        float sv = 0.f;
        for (int j = 0; j < k; ++j) sv += vw[d * k + j];
        Beff[ch] = qb[d] * sv + vb[d];

        for (int l = 0; l < 6; ++l) {
            float s2 = 0.f;
            for (int i = l + 1; i < 7; ++i) s2 += hv[i];
            Corr[l * 768 + ch] = qb[d] * s2;
        }
        return;
    }
    int i = blockIdx.x * 256 + threadIdx.x;
    const float* src;
    unsigned short* dst;
    int j;
    if (i < XQ) {
        j = i * 4; src = x; dst = xb;
    } else if (i < XQ + WQ) {
        j = (i - XQ) * 4;
        int row = j >> 10;                 // /1024
        src = (row < 256) ? Wv : Wq;       // stitched W1
        dst = W1b;
    } else {
        j = (i - XQ - WQ) * 4; src = Wo; dst = Wob;
    }
    float4v v = *(const float4v*)(src + j);
    us4 o;
    o[0] = f2b(v[0]); o[1] = f2b(v[1]); o[2] = f2b(v[2]); o[3] = f2b(v[3]);
    *(us4*)(dst + j) = o;
}

// ---------------------------------------------------------------------------
// GEMM (counted-vmcnt 3-buffer pipeline + XOR bank swizzle + XCD swizzle):
//   C[M,N] = A[M,K] * BT[N,K]^T. BM=128, BN=64, BK=64, 256 thr (4 waves 2x2),
//   wave tile 64x32, acc 4x2 of mfma_f32_16x16x32_bf16.
//   LDS 3*(16K+8K)=72KB -> 2 blocks/CU; grid 512 = 2/CU.
//   Pipeline: tiles t+1,t+2 in flight; per iter wait vmcnt(6) (t+1 landed,
//   t+2's 6 loads outstanding) + raw s_barrier. Never vmcnt(0) mid-loop.
//   Swizzle: 16B col-group g of row r lives at g^(r&7) (both-sides: applied
//   to pre-swizzled global source of global_load_lds AND to ds_read addr).
// OUT_MODE 0: bf16 store. OUT_MODE 1: f32 store + bias[col].
// ---------------------------------------------------------------------------
template <int OUT_MODE>
__global__ __launch_bounds__(256) void gemm_pipe(
    const unsigned short* __restrict__ A, const unsigned short* __restrict__ BT,
    unsigned short* __restrict__ Cb, float* __restrict__ Cf,
    const float* __restrict__ bias, int M, int N, int K)
{
    __shared__ unsigned short As[3][128 * 64];
    __shared__ unsigned short Bs[3][64 * 64];

    // XCD-aware remap (512 blocks, 512%8==0 -> bijective): consecutive tiles
    // (sharing an A row-panel) land on the same XCD's L2.
    const int nbx = N >> 6;                       // 16
    int orig = blockIdx.y * nbx + blockIdx.x;
    int nwg  = (M >> 7) * nbx;                    // 512
    int wg   = (orig & 7) * (nwg >> 3) + (orig >> 3);
    const int m0 = (wg / nbx) * 128, n0 = (wg % nbx) * 64;

    const int tid  = threadIdx.x;
    const int wid  = tid >> 6;
    const int lane = tid & 63;
    const int wr   = wid >> 1, wc = wid & 1;          // 2x2 wave grid
    const int fr   = lane & 15, fq = lane >> 4;
    const int swz  = fr & 7;                          // = row&7 for all frags

    f32x4 acc[4][2] = {};

    const unsigned short* Abase = A  + (size_t)m0 * K;
    const unsigned short* Bbase = BT + (size_t)n0 * K;

    // stage tile t into buffer buf. LDS chunk d (16B) holds global
    // (row = d>>3, colgrp = (d&7) ^ ((d>>3)&7))  [inverse == forward: XOR].
    auto stage = [&](int buf, int t) {
        const unsigned short* Ab = Abase + (t << 6);
        const unsigned short* Bb = Bbase + (t << 6);
#pragma unroll
        for (int i = 0; i < 4; ++i) {
            int d = wid * 256 + i * 64 + lane;
            lds16(Ab + (size_t)(d >> 3) * K + (((d & 7) ^ ((d >> 3) & 7)) * 8),
                  &As[buf][(wid * 256 + i * 64) * 8]);
        }
#pragma unroll
        for (int i = 0; i < 2; ++i) {
            int d = wid * 128 + i * 64 + lane;
            lds16(Bb + (size_t)(d >> 3) * K + (((d & 7) ^ ((d >> 3) & 7)) * 8),
                  &Bs[buf][(wid * 128 + i * 64) * 8]);
        }
    };

    auto compute = [&](int buf) {
        const unsigned short* as = As[buf];
        const unsigned short* bs = Bs[buf];
#pragma unroll
        for (int s = 0; s < 2; ++s) {                    // two K=32 slabs
            bf16x8 a[4], b[2];
#pragma unroll
            for (int mi = 0; mi < 4; ++mi)
                a[mi] = *(const bf16x8*)(as + (wr * 64 + mi * 16 + fr) * 64
                                            + ((s * 4 + fq) ^ swz) * 8);
#pragma unroll
            for (int ni = 0; ni < 2; ++ni)
                b[ni] = *(const bf16x8*)(bs + (wc * 32 + ni * 16 + fr) * 64
                                            + ((s * 4 + fq) ^ swz) * 8);
#pragma unroll
            for (int mi = 0; mi < 4; ++mi)
#pragma unroll
                for (int ni = 0; ni < 2; ++ni)
                    acc[mi][ni] = __builtin_amdgcn_mfma_f32_16x16x32_bf16(a[mi], b[ni], acc[mi][ni], 0, 0, 0);
        }
    };

    const int NT = K >> 6;   // 16 K-tiles (>= 3 assumed)
    stage(0, 0);
    stage(1, 1);
    asm volatile("s_waitcnt vmcnt(6)" ::: "memory");   // tile 0 landed
    __builtin_amdgcn_s_barrier();
    asm volatile("" ::: "memory");

    for (int t = 0; t < NT; ++t) {
        if (t + 2 < NT) stage((t + 2) % 3, t + 2);
        compute(t % 3);
        if (t + 1 < NT) {
            if (t + 2 < NT) {
                asm volatile("s_waitcnt vmcnt(6)" ::: "memory");  // t+1 landed
            } else {
                asm volatile("s_waitcnt vmcnt(0)" ::: "memory");  // drain tail
            }
            __builtin_amdgcn_s_barrier();
            asm volatile("" ::: "memory");
        }
    }

    // epilogue: C/D layout col=lane&15, row=(lane>>4)*4+j  [m89-verified]
#pragma unroll
    for (int mi = 0; mi < 4; ++mi) {
#pragma unroll
        for (int ni = 0; ni < 2; ++ni) {
            int col  = n0 + wc * 32 + ni * 16 + fr;
            int rowb = m0 + wr * 64 + mi * 16 + fq * 4;
#pragma unroll
            for (int j = 0; j < 4; ++j) {
                float v = acc[mi][ni][j];
                if (OUT_MODE == 0) {
                    Cb[(size_t)(rowb + j) * N + col] = f2b(v);
                } else {
                    Cf[(size_t)(rowb + j) * N + col] = v + bias[col];
                }
            }
        }
    }
}

// ---------------------------------------------------------------------------
// conv: V[m][e] = T[m][e] for e<256 (v0 pass-through);
//       else causal FIR over l with combined taps + boundary corr.
// ---------------------------------------------------------------------------
__global__ __launch_bounds__(256) void conv_kernel(
    const unsigned short* __restrict__ T, unsigned short* __restrict__ V,
    const float* __restrict__ H, const float* __restrict__ Beff,
    const float* __restrict__ Corr)
{
    int w  = blockIdx.x * 256 + threadIdx.x;   // 4096*256 work items
    int m  = w >> 8;
    int c4 = w & 255;
    int e0 = c4 * 4;
    const unsigned short* tp = T + (size_t)m * EDIM + e0;
    unsigned short*       vp = V + (size_t)m * EDIM + e0;
    if (e0 < 256) {                       // v0 pass-through
        *(u32x2*)vp = *(const u32x2*)tp;
        return;
    }
    int l  = m & (L_SEQ - 1);
    int ch = e0 - 256;
    float4v acc = *(const float4v*)(Beff + ch);
    int ni = (l < 12) ? l : 12;
    for (int i = 0; i <= ni; ++i) {
        float4v h = *(const float4v*)(H + i * 768 + ch);
        us4 t = *(const us4*)(tp - (size_t)i * EDIM);
        acc[0] += h[0] * b2f(t[0]);
        acc[1] += h[1] * b2f(t[1]);
        acc[2] += h[2] * b2f(t[2]);
        acc[3] += h[3] * b2f(t[3]);
    }
    if (l < 6) {   // bias boundary correction (intermediate zero-padding)
        float4v c = *(const float4v*)(Corr + l * 768 + ch);
        acc[0] -= c[0]; acc[1] -= c[1]; acc[2] -= c[2]; acc[3] -= c[3];
    }
    us4 o;
    o[0] = f2b(acc[0]); o[1] = f2b(acc[1]); o[2] = f2b(acc[2]); o[3] = f2b(acc[3]);
    *(us4*)vp = o;
}

// ---------------------------------------------------------------------------
extern "C" void kernel_launch(void* const* d_in, const int* in_sizes, int n_in,
                              void* d_out, int out_size, void* d_ws, size_t ws_size,
                              hipStream_t stream)
{
    const float* x  = (const float*)d_in[0];
    const float* Wq = (const float*)d_in[1];
    // d_in[2] = Wk (dead: attention output is multiplied by 0.0)
    const float* Wv = (const float*)d_in[3];
    const float* Wo = (const float*)d_in[4];
    const float* bo = (const float*)d_in[5];

    uint8_t* ws = (uint8_t*)d_ws;
    unsigned short* xb  = (unsigned short*)(ws);                    //  8 MB
    unsigned short* W1b = (unsigned short*)(ws + (8u  << 20));      //  2 MB
    unsigned short* Wob = (unsigned short*)(ws + (10u << 20));      //  2 MB
    unsigned short* T   = (unsigned short*)(ws + (12u << 20));      //  8 MB
    unsigned short* V   = (unsigned short*)(ws + (20u << 20));      //  8 MB
    float* H    = (float*)(ws + (28u << 20));                        // 40 KB
    float* Beff = (float*)(ws + (28u << 20) + (64u << 10));          //  3 KB
    float* Corr = (float*)(ws + (28u << 20) + (96u << 10));          // 18 KB

    prep_kernel<<<6147, 256, 0, stream>>>(
        x, Wq, Wv, Wo, xb, W1b, Wob,
        (const float*)d_in[6],  (const float*)d_in[7],
        (const float*)d_in[10], (const float*)d_in[11],
        (const float*)d_in[12], (const float*)d_in[13],
        (const float*)d_in[16], (const float*)d_in[17],
        (const float*)d_in[18], (const float*)d_in[19],
        (const float*)d_in[22], (const float*)d_in[23],
        H, Beff, Corr);

    dim3 gg(EDIM / 64, MTOT / 128);   // (16, 32) = 512 blocks, 2 per CU
    gemm_pipe<0><<<gg, 256, 0, stream>>>(xb, W1b, T, nullptr, nullptr, MTOT, EDIM, EDIM);

    conv_kernel<<<4096, 256, 0, stream>>>(T, V, H, Beff, Corr);

    gemm_pipe<1><<<gg, 256, 0, stream>>>(V, Wob, nullptr, (float*)d_out, bo, MTOT, EDIM, EDIM);
}

// Round 4
// 57.724 us; speedup vs baseline: 1.5203x; 1.1133x over previous
//
#include <hip/hip_runtime.h>
#include <hip/hip_bf16.h>
#include <stdint.h>

// Problem constants: B=2, L=2048, E=1024, H=16, HD=64, G=4.
#define L_SEQ 2048
#define MTOT  4096   // B*L
#define EDIM  1024

typedef __attribute__((ext_vector_type(8))) short bf16x8;   // 8 bf16 (4 VGPRs)
typedef __attribute__((ext_vector_type(4))) float f32x4;
typedef __attribute__((ext_vector_type(4))) float float4v;
typedef __attribute__((ext_vector_type(4))) unsigned short us4;
typedef __attribute__((ext_vector_type(2))) unsigned int u32x2;

__device__ __forceinline__ unsigned short f2b(float f) {
    union { float f; unsigned u; } v; v.f = f;
    return (unsigned short)((v.u + 0x7FFFu + ((v.u >> 16) & 1u)) >> 16);  // RNE
}
__device__ __forceinline__ float b2f(unsigned short h) {
    union { unsigned u; float f; } v; v.u = ((unsigned)h) << 16;
    return v.f;
}

__device__ __forceinline__ void lds16(const void* g, void* l) {
    __builtin_amdgcn_global_load_lds((const __attribute__((address_space(1))) void*)g,
                                     (__attribute__((address_space(3))) void*)l, 16, 0, 0);
}

// ---------------------------------------------------------------------------
// prep: convert x -> bf16; stitch W1 = [Wv rows 0..255 ; Wq rows 256..1023];
//       convert Wo -> bf16. Blocks >= 6144 compute the composed FIR taps.
// ---------------------------------------------------------------------------
__global__ __launch_bounds__(256) void prep_kernel(
    const float* __restrict__ x, const float* __restrict__ Wq,
    const float* __restrict__ Wv, const float* __restrict__ Wo,
    unsigned short* __restrict__ xb, unsigned short* __restrict__ W1b,
    unsigned short* __restrict__ Wob,
    const float* __restrict__ q3w, const float* __restrict__ q3b,
    const float* __restrict__ v3w, const float* __restrict__ v3b,
    const float* __restrict__ q5w, const float* __restrict__ q5b,
    const float* __restrict__ v5w, const float* __restrict__ v5b,
    const float* __restrict__ q7w, const float* __restrict__ q7b,
    const float* __restrict__ v7w, const float* __restrict__ v7b,
    float* __restrict__ H, float* __restrict__ Beff, float* __restrict__ Corr)
{
    const int XQ = (MTOT * EDIM) / 4;   // 1,048,576 quads
    const int WQ = (EDIM * EDIM) / 4;   //   262,144 quads
    if (blockIdx.x >= 6144) {
        // taps: compose the two causal depthwise convs per channel.
        //   dwconv taps h[i] = w[k-1-i]; chain h = hq (*) hv (len 2k-1<=13),
        //   beff = vb + qb*sum(vw); boundary (l<k-1): intermediate zero-pad
        //   drops qb for taps i>l -> Corr[l][ch] = qb*sum_{i=l+1..} hv[i].
        int ch = (blockIdx.x - 6144) * 256 + threadIdx.x;   // [0,768)
        int g = ch >> 8;          // 0,1,2 -> ksz 3,5,7
        int d = ch & 63;
        int k = 3 + 2 * g;
        const float* qw = (g == 0) ? q3w : (g == 1) ? q5w : q7w;
        const float* qb = (g == 0) ? q3b : (g == 1) ? q5b : q7b;
        const float* vw = (g == 0) ? v3w : (g == 1) ? v5w : v7w;
        const float* vb = (g == 0) ? v3b : (g == 1) ? v5b : v7b;

        float hq[7], hv[7];
        for (int i = 0; i < 7; ++i) { hq[i] = 0.f; hv[i] = 0.f; }
        for (int i = 0; i < k; ++i) {
            hq[i] = qw[d * k + (k - 1 - i)];
            hv[i] = vw[d * k + (k - 1 - i)];
        }
        float h[13];
        for (int i = 0; i < 13; ++i) h[i] = 0.f;
        for (int a = 0; a < 7; ++a)
            for (int b = 0; b < 7; ++b)
                h[a + b] += hq[a] * hv[b];
        for (int i = 0; i < 13; ++i) H[i * 768 + ch] = h[i];

        float sv = 0.f;
        for (int j = 0; j < k; ++j) sv += vw[d * k + j];
        Beff[ch] = qb[d] * sv + vb[d];

        for (int l = 0; l < 6; ++l) {
            float s2 = 0.f;
            for (int i = l + 1; i < 7; ++i) s2 += hv[i];
            Corr[l * 768 + ch] = qb[d] * s2;
        }
        return;
    }
    int i = blockIdx.x * 256 + threadIdx.x;
    const float* src;
    unsigned short* dst;
    int j;
    if (i < XQ) {
        j = i * 4; src = x; dst = xb;
    } else if (i < XQ + WQ) {
        j = (i - XQ) * 4;
        int row = j >> 10;                 // /1024
        src = (row < 256) ? Wv : Wq;       // stitched W1
        dst = W1b;
    } else {
        j = (i - XQ - WQ) * 4; src = Wo; dst = Wob;
    }
    float4v v = *(const float4v*)(src + j);
    us4 o;
    o[0] = f2b(v[0]); o[1] = f2b(v[1]); o[2] = f2b(v[2]); o[3] = f2b(v[3]);
    *(us4*)(dst + j) = o;
}

// ---------------------------------------------------------------------------
// GEMM (8-wave, counted-vmcnt 3-buffer pipeline, XOR bank swizzle, XCD swz):
//   C[M,N] = A[M,K] * BT[N,K]^T. BM=128, BN=64, BK=64, 512 thr = 8 waves in
//   4x2 grid, wave tile 32x32, acc 2x2 of mfma_f32_16x16x32_bf16.
//   LDS 3*(16K+8K)=72KB -> 2 blocks/CU -> 16 waves/CU = 4 waves/SIMD.
//   Per iter per thread: 3 global_load_lds (2 A + 1 B); depth-2 prefetch;
//   wait vmcnt(3) (next tile landed, tile-after's 3 in flight). Never
//   vmcnt(0) mid-loop. Swizzle: 16B col-group g of row r at g^(r&7), applied
//   to pre-swizzled global source AND ds_read addr (XOR involution).
// OUT_MODE 0: bf16 store. OUT_MODE 1: f32 store + bias[col].
// ---------------------------------------------------------------------------
template <int OUT_MODE>
__global__ __launch_bounds__(512, 4) void gemm_pipe(
    const unsigned short* __restrict__ A, const unsigned short* __restrict__ BT,
    unsigned short* __restrict__ Cb, float* __restrict__ Cf,
    const float* __restrict__ bias, int M, int N, int K)
{
    __shared__ unsigned short As[3][128 * 64];
    __shared__ unsigned short Bs[3][64 * 64];

    // XCD-aware remap (512 blocks, 512%8==0 -> bijective).
    const int nbx = N >> 6;                       // 16
    int orig = blockIdx.y * nbx + blockIdx.x;
    int nwg  = (M >> 7) * nbx;                    // 512
    int wg   = (orig & 7) * (nwg >> 3) + (orig >> 3);
    const int m0 = (wg / nbx) * 128, n0 = (wg % nbx) * 64;

    const int tid  = threadIdx.x;
    const int wid  = tid >> 6;                    // 0..7
    const int lane = tid & 63;
    const int wr   = wid >> 1, wc = wid & 1;      // 4x2 wave grid, 32x32 tiles
    const int fr   = lane & 15, fq = lane >> 4;

    f32x4 acc[2][2] = {};

    const unsigned short* Aptr = A  + (size_t)m0 * K;
    const unsigned short* Bptr = BT + (size_t)n0 * K;

    // staging chunks (16B): A has 1024 (rows 128 x 8 colgrps), B has 512.
    // thread owns A-chunks {tid, 512+tid} and B-chunk {tid}. LDS dest is
    // linear (chunk*16B); global source pre-swizzled: colgrp ^= row&7.
    const int cA1 = 512 + tid;
    const size_t offA0 = (size_t)(tid >> 3) * K + (((tid & 7) ^ ((tid >> 3) & 7)) * 8);
    const size_t offA1 = (size_t)(cA1 >> 3) * K + (((cA1 & 7) ^ ((cA1 >> 3) & 7)) * 8);
    const size_t offB  = offA0;                   // same formula, B base

    auto stage = [&](int buf, int t) {
        const unsigned short* Ab = Aptr + (t << 6);
        const unsigned short* Bb = Bptr + (t << 6);
        lds16(Ab + offA0, &As[buf][(wid * 64) * 8]);
        lds16(Ab + offA1, &As[buf][(512 + wid * 64) * 8]);
        lds16(Bb + offB,  &Bs[buf][(wid * 64) * 8]);
    };

    auto compute = [&](int buf) {
        const unsigned short* as = As[buf];
        const unsigned short* bs = Bs[buf];
#pragma unroll
        for (int s = 0; s < 2; ++s) {                    // two K=32 slabs
            bf16x8 a[2], b[2];
#pragma unroll
            for (int mi = 0; mi < 2; ++mi) {
                int row = wr * 32 + mi * 16 + fr;
                a[mi] = *(const bf16x8*)(as + row * 64 + (((s * 4 + fq) ^ (row & 7)) * 8));
            }
#pragma unroll
            for (int ni = 0; ni < 2; ++ni) {
                int row = wc * 32 + ni * 16 + fr;
                b[ni] = *(const bf16x8*)(bs + row * 64 + (((s * 4 + fq) ^ (row & 7)) * 8));
            }
#pragma unroll
            for (int mi = 0; mi < 2; ++mi)
#pragma unroll
                for (int ni = 0; ni < 2; ++ni)
                    acc[mi][ni] = __builtin_amdgcn_mfma_f32_16x16x32_bf16(a[mi], b[ni], acc[mi][ni], 0, 0, 0);
        }
    };

    const int NT = K >> 6;   // 16 K-tiles (>= 3 assumed)
    stage(0, 0);
    stage(1, 1);
    asm volatile("s_waitcnt vmcnt(3)" ::: "memory");   // tile 0 landed
    __builtin_amdgcn_s_barrier();
    asm volatile("" ::: "memory");

    for (int t = 0; t < NT; ++t) {
        if (t + 2 < NT) stage((t + 2) % 3, t + 2);
        compute(t % 3);
        if (t + 1 < NT) {
            if (t + 2 < NT) {
                asm volatile("s_waitcnt vmcnt(3)" ::: "memory");  // t+1 landed
            } else {
                asm volatile("s_waitcnt vmcnt(0)" ::: "memory");  // drain tail
            }
            __builtin_amdgcn_s_barrier();
            asm volatile("" ::: "memory");
        }
    }

    // epilogue: C/D layout col=lane&15, row=(lane>>4)*4+j  [m89-verified]
#pragma unroll
    for (int mi = 0; mi < 2; ++mi) {
#pragma unroll
        for (int ni = 0; ni < 2; ++ni) {
            int col  = n0 + wc * 32 + ni * 16 + fr;
            int rowb = m0 + wr * 32 + mi * 16 + fq * 4;
#pragma unroll
            for (int j = 0; j < 4; ++j) {
                float v = acc[mi][ni][j];
                if (OUT_MODE == 0) {
                    Cb[(size_t)(rowb + j) * N + col] = f2b(v);
                } else {
                    Cf[(size_t)(rowb + j) * N + col] = v + bias[col];
                }
            }
        }
    }
}

// ---------------------------------------------------------------------------
// conv: V[m][e] = T[m][e] for e<256 (v0 pass-through);
//       else causal FIR over l with combined taps + boundary corr.
// Thread handles 4 channels x 2 consecutive positions (m even): adjacent
// positions share 12/13 FIR rows -> 14 row-loads per 2 outputs.
// ---------------------------------------------------------------------------
__global__ __launch_bounds__(256) void conv_kernel(
    const unsigned short* __restrict__ T, unsigned short* __restrict__ V,
    const float* __restrict__ H, const float* __restrict__ Beff,
    const float* __restrict__ Corr)
{
    int w  = blockIdx.x * 256 + threadIdx.x;   // 2048*256 work items
    int m  = (w >> 8) * 2;                     // even position; pair never
    int e0 = (w & 255) * 4;                    // crosses batch boundary
    const unsigned short* tp = T + (size_t)m * EDIM + e0;
    unsigned short*       vp = V + (size_t)m * EDIM + e0;
    if (e0 < 256) {                       // v0 pass-through (both rows)
        *(u32x2*)vp = *(const u32x2*)tp;
        *(u32x2*)(vp + EDIM) = *(const u32x2*)(tp + EDIM);
        return;
    }
    int l  = m & (L_SEQ - 1);
    int ch = e0 - 256;
    float4v b4 = *(const float4v*)(Beff + ch);
    float4v acc0 = b4, acc1 = b4;

    // acc1 tap j=0: row m+1
    {
        float4v h = *(const float4v*)(H + ch);      // H[0]
        us4 t = *(const us4*)(tp + EDIM);
        acc1[0] += h[0] * b2f(t[0]); acc1[1] += h[1] * b2f(t[1]);
        acc1[2] += h[2] * b2f(t[2]); acc1[3] += h[3] * b2f(t[3]);
    }
    int ni = (l < 12) ? l : 12;
    for (int i = 0; i <= ni; ++i) {                 // row m-i, taps h[i]/h[i+1]
        us4 t = *(const us4*)(tp - (size_t)i * EDIM);
        float4v h0 = *(const float4v*)(H + i * 768 + ch);
        acc0[0] += h0[0] * b2f(t[0]); acc0[1] += h0[1] * b2f(t[1]);
        acc0[2] += h0[2] * b2f(t[2]); acc0[3] += h0[3] * b2f(t[3]);
        if (i < 12) {
            float4v h1 = *(const float4v*)(H + (i + 1) * 768 + ch);
            acc1[0] += h1[0] * b2f(t[0]); acc1[1] += h1[1] * b2f(t[1]);
            acc1[2] += h1[2] * b2f(t[2]); acc1[3] += h1[3] * b2f(t[3]);
        }
    }
    if (l < 6) {   // bias boundary correction (intermediate zero-padding)
        float4v c = *(const float4v*)(Corr + l * 768 + ch);
        acc0[0] -= c[0]; acc0[1] -= c[1]; acc0[2] -= c[2]; acc0[3] -= c[3];
    }
    if (l + 1 < 6) {
        float4v c = *(const float4v*)(Corr + (l + 1) * 768 + ch);
        acc1[0] -= c[0]; acc1[1] -= c[1]; acc1[2] -= c[2]; acc1[3] -= c[3];
    }
    us4 o0, o1;
    o0[0] = f2b(acc0[0]); o0[1] = f2b(acc0[1]); o0[2] = f2b(acc0[2]); o0[3] = f2b(acc0[3]);
    o1[0] = f2b(acc1[0]); o1[1] = f2b(acc1[1]); o1[2] = f2b(acc1[2]); o1[3] = f2b(acc1[3]);
    *(us4*)vp = o0;
    *(us4*)(vp + EDIM) = o1;
}

// ---------------------------------------------------------------------------
extern "C" void kernel_launch(void* const* d_in, const int* in_sizes, int n_in,
                              void* d_out, int out_size, void* d_ws, size_t ws_size,
                              hipStream_t stream)
{
    const float* x  = (const float*)d_in[0];
    const float* Wq = (const float*)d_in[1];
    // d_in[2] = Wk (dead: attention output is multiplied by 0.0)
    const float* Wv = (const float*)d_in[3];
    const float* Wo = (const float*)d_in[4];
    const float* bo = (const float*)d_in[5];

    uint8_t* ws = (uint8_t*)d_ws;
    unsigned short* xb  = (unsigned short*)(ws);                    //  8 MB
    unsigned short* W1b = (unsigned short*)(ws + (8u  << 20));      //  2 MB
    unsigned short* Wob = (unsigned short*)(ws + (10u << 20));      //  2 MB
    unsigned short* T   = (unsigned short*)(ws + (12u << 20));      //  8 MB
    unsigned short* V   = (unsigned short*)(ws + (20u << 20));      //  8 MB
    float* H    = (float*)(ws + (28u << 20));                        // 40 KB
    float* Beff = (float*)(ws + (28u << 20) + (64u << 10));          //  3 KB
    float* Corr = (float*)(ws + (28u << 20) + (96u << 10));          // 18 KB

    prep_kernel<<<6147, 256, 0, stream>>>(
        x, Wq, Wv, Wo, xb, W1b, Wob,
        (const float*)d_in[6],  (const float*)d_in[7],
        (const float*)d_in[10], (const float*)d_in[11],
        (const float*)d_in[12], (const float*)d_in[13],
        (const float*)d_in[16], (const float*)d_in[17],
        (const float*)d_in[18], (const float*)d_in[19],
        (const float*)d_in[22], (const float*)d_in[23],
        H, Beff, Corr);

    dim3 gg(EDIM / 64, MTOT / 128);   // (16, 32) = 512 blocks, 2 per CU
    gemm_pipe<0><<<gg, 512, 0, stream>>>(xb, W1b, T, nullptr, nullptr, MTOT, EDIM, EDIM);

    conv_kernel<<<2048, 256, 0, stream>>>(T, V, H, Beff, Corr);

    gemm_pipe<1><<<gg, 512, 0, stream>>>(V, Wob, nullptr, (float*)d_out, bo, MTOT, EDIM, EDIM);
}

// Round 5
// 55.609 us; speedup vs baseline: 1.5782x; 1.0380x over previous
//
#include <hip/hip_runtime.h>
#include <hip/hip_bf16.h>
#include <stdint.h>

// Problem constants: B=2, L=2048, E=1024, H=16, HD=64, G=4.
#define L_SEQ 2048
#define MTOT  4096   // B*L
#define EDIM  1024

typedef __attribute__((ext_vector_type(8))) short bf16x8;   // 8 bf16 (4 VGPRs)
typedef __attribute__((ext_vector_type(4))) float f32x4;
typedef __attribute__((ext_vector_type(4))) float float4v;
typedef __attribute__((ext_vector_type(4))) unsigned short us4;
typedef __attribute__((ext_vector_type(2))) unsigned int u32x2;

__device__ __forceinline__ unsigned short f2b(float f) {
    union { float f; unsigned u; } v; v.f = f;
    return (unsigned short)((v.u + 0x7FFFu + ((v.u >> 16) & 1u)) >> 16);  // RNE
}
__device__ __forceinline__ float b2f(unsigned short h) {
    union { unsigned u; float f; } v; v.u = ((unsigned)h) << 16;
    return v.f;
}

__device__ __forceinline__ void lds16(const void* g, void* l) {
    __builtin_amdgcn_global_load_lds((const __attribute__((address_space(1))) void*)g,
                                     (__attribute__((address_space(3))) void*)l, 16, 0, 0);
}

// ---------------------------------------------------------------------------
// prep: convert x -> bf16; stitch W1 = [Wv rows 0..255 ; Wq rows 256..1023];
//       convert Wo -> bf16. Blocks >= 6144 compute the composed FIR taps.
// ---------------------------------------------------------------------------
__global__ __launch_bounds__(256) void prep_kernel(
    const float* __restrict__ x, const float* __restrict__ Wq,
    const float* __restrict__ Wv, const float* __restrict__ Wo,
    unsigned short* __restrict__ xb, unsigned short* __restrict__ W1b,
    unsigned short* __restrict__ Wob,
    const float* __restrict__ q3w, const float* __restrict__ q3b,
    const float* __restrict__ v3w, const float* __restrict__ v3b,
    const float* __restrict__ q5w, const float* __restrict__ q5b,
    const float* __restrict__ v5w, const float* __restrict__ v5b,
    const float* __restrict__ q7w, const float* __restrict__ q7b,
    const float* __restrict__ v7w, const float* __restrict__ v7b,
    float* __restrict__ H, float* __restrict__ Beff, float* __restrict__ Corr)
{
    const int XQ = (MTOT * EDIM) / 4;   // 1,048,576 quads
    const int WQ = (EDIM * EDIM) / 4;   //   262,144 quads
    if (blockIdx.x >= 6144) {
        // taps: compose the two causal depthwise convs per channel.
        //   dwconv taps h[i] = w[k-1-i]; chain h = hq (*) hv (len 2k-1<=13),
        //   beff = vb + qb*sum(vw); boundary (l<k-1): intermediate zero-pad
        //   drops qb for taps i>l -> Corr[l][ch] = qb*sum_{i=l+1..} hv[i].
        int ch = (blockIdx.x - 6144) * 256 + threadIdx.x;   // [0,768)
        int g = ch >> 8;          // 0,1,2 -> ksz 3,5,7
        int d = ch & 63;
        int k = 3 + 2 * g;
        const float* qw = (g == 0) ? q3w : (g == 1) ? q5w : q7w;
        const float* qb = (g == 0) ? q3b : (g == 1) ? q5b : q7b;
        const float* vw = (g == 0) ? v3w : (g == 1) ? v5w : v7w;
        const float* vb = (g == 0) ? v3b : (g == 1) ? v5b : v7b;

        float hq[7], hv[7];
        for (int i = 0; i < 7; ++i) { hq[i] = 0.f; hv[i] = 0.f; }
        for (int i = 0; i < k; ++i) {
            hq[i] = qw[d * k + (k - 1 - i)];
            hv[i] = vw[d * k + (k - 1 - i)];
        }
        float h[13];
        for (int i = 0; i < 13; ++i) h[i] = 0.f;
        for (int a = 0; a < 7; ++a)
            for (int b = 0; b < 7; ++b)
                h[a + b] += hq[a] * hv[b];
        for (int i = 0; i < 13; ++i) H[i * 768 + ch] = h[i];

        float sv = 0.f;
        for (int j = 0; j < k; ++j) sv += vw[d * k + j];
        Beff[ch] = qb[d] * sv + vb[d];

        for (int l = 0; l < 6; ++l) {
            float s2 = 0.f;
            for (int i = l + 1; i < 7; ++i) s2 += hv[i];
            Corr[l * 768 + ch] = qb[d] * s2;
        }
        return;
    }
    int i = blockIdx.x * 256 + threadIdx.x;
    const float* src;
    unsigned short* dst;
    int j;
    if (i < XQ) {
        j = i * 4; src = x; dst = xb;
    } else if (i < XQ + WQ) {
        j = (i - XQ) * 4;
        int row = j >> 10;                 // /1024
        src = (row < 256) ? Wv : Wq;       // stitched W1
        dst = W1b;
    } else {
        j = (i - XQ - WQ) * 4; src = Wo; dst = Wob;
    }
    float4v v = *(const float4v*)(src + j);
    us4 o;
    o[0] = f2b(v[0]); o[1] = f2b(v[1]); o[2] = f2b(v[2]); o[3] = f2b(v[3]);
    *(us4*)(dst + j) = o;
}

// ---------------------------------------------------------------------------
// GEMM (8-wave K-split, 64x64 wave tiles, counted-vmcnt 3-buffer pipeline):
//   C[M,N] = A[M,K] * BT[N,K]^T. BM=BN=128, BK=64, 512 thr = 8 waves:
//   2x2 spatial (wr,wc) x 2 K-halves (kh). Wave tile 64x64, acc 4x4 of
//   mfma_f32_16x16x32_bf16; wave kh handles K-slab kh*32 of each tile.
//   LDS-read traffic = M*N*K*2/32 = 268 MB/GEMM (was 537 MB at 32x32 tiles).
//   LDS: 3 buffers x (16KB A + 16KB B) = 96KB -> 1 block/CU, 8 waves/CU.
//   Pipeline: depth 2, 4 loads/thread/tile, steady wait vmcnt(4).
//   End: kh=1 waves dump partial acc to LDS (bank-staggered), kh=0 merge
//   and store. Swizzles: colgrp^row&7 (LDS banks), XCD remap (L2).
// OUT_MODE 0: bf16 store. OUT_MODE 1: f32 store + bias[col].
// ---------------------------------------------------------------------------
template <int OUT_MODE>
__global__ __launch_bounds__(512, 2) void gemm_ks(
    const unsigned short* __restrict__ A, const unsigned short* __restrict__ BT,
    unsigned short* __restrict__ Cb, float* __restrict__ Cf,
    const float* __restrict__ bias, int M, int N, int K)
{
    // buffer i: A at sh+i*16384, B at sh+i*16384+8192 (shorts). 96KB total.
    __shared__ unsigned short sh[3 * 16384];

    // XCD-aware remap (256 blocks, %8==0 -> bijective).
    const int nbx = N >> 7;                       // 8
    int orig = blockIdx.y * nbx + blockIdx.x;
    int nwg  = (M >> 7) * nbx;                    // 256
    int wg   = (orig & 7) * (nwg >> 3) + (orig >> 3);
    const int m0 = (wg / nbx) * 128, n0 = (wg % nbx) * 128;

    const int tid  = threadIdx.x;
    const int wid  = tid >> 6;                    // 0..7
    const int lane = tid & 63;
    const int wr   = wid >> 2;                    // 2x2 spatial
    const int wc   = (wid >> 1) & 1;
    const int kh   = wid & 1;                     // K-half
    const int fr   = lane & 15, fq = lane >> 4;

    f32x4 acc[4][4] = {};

    const unsigned short* Aptr = A  + (size_t)m0 * K;
    const unsigned short* Bptr = BT + (size_t)n0 * K;

    // staging: tile = 128 rows x 8 colgrps(16B) = 1024 chunks; thread owns
    // chunks {tid, tid+512} of A and of B. LDS dest linear (chunk*16B);
    // global source pre-swizzled: colgrp ^= row&7. chunk+512 => row+64,
    // same colgrp swizzle (64 = 0 mod 8).
    const size_t offA0 = (size_t)(tid >> 3) * K + (((tid & 7) ^ ((tid >> 3) & 7)) * 8);
    const size_t offA1 = offA0 + (size_t)64 * K;

    auto stage = [&](int buf, int t) {
        unsigned short* Al = sh + buf * 16384;
        unsigned short* Bl = Al + 8192;
        const unsigned short* Ag = Aptr + (t << 6);
        const unsigned short* Bg = Bptr + (t << 6);
        lds16(Ag + offA0, Al + tid * 8);
        lds16(Ag + offA1, Al + (512 + tid) * 8);
        lds16(Bg + offA0, Bl + tid * 8);
        lds16(Bg + offA1, Bl + (512 + tid) * 8);
    };

    auto compute = [&](int buf) {
        const unsigned short* as = sh + buf * 16384;
        const unsigned short* bs = as + 8192;
        bf16x8 a[4], b[4];
#pragma unroll
        for (int mi = 0; mi < 4; ++mi) {
            int row = wr * 64 + mi * 16 + fr;
            a[mi] = *(const bf16x8*)(as + row * 64 + (((kh * 4 + fq) ^ (row & 7)) * 8));
        }
#pragma unroll
        for (int ni = 0; ni < 4; ++ni) {
            int row = wc * 64 + ni * 16 + fr;
            b[ni] = *(const bf16x8*)(bs + row * 64 + (((kh * 4 + fq) ^ (row & 7)) * 8));
        }
#pragma unroll
        for (int mi = 0; mi < 4; ++mi)
#pragma unroll
            for (int ni = 0; ni < 4; ++ni)
                acc[mi][ni] = __builtin_amdgcn_mfma_f32_16x16x32_bf16(a[mi], b[ni], acc[mi][ni], 0, 0, 0);
    };

    const int NT = K >> 6;   // 16 K-tiles (>= 3 assumed)
    stage(0, 0);
    stage(1, 1);
    asm volatile("s_waitcnt vmcnt(4)" ::: "memory");   // tile 0 landed
    __builtin_amdgcn_s_barrier();
    asm volatile("" ::: "memory");

    for (int t = 0; t < NT; ++t) {
        if (t + 2 < NT) stage((t + 2) % 3, t + 2);
        compute(t % 3);
        if (t + 1 < NT) {
            if (t + 2 < NT) {
                asm volatile("s_waitcnt vmcnt(4)" ::: "memory");  // t+1 landed
            } else {
                asm volatile("s_waitcnt vmcnt(0)" ::: "memory");  // drain tail
            }
            __builtin_amdgcn_s_barrier();
            asm volatile("" ::: "memory");
        }
    }

    // ---- K-split merge: kh=1 dumps partials to LDS, kh=0 adds. ----
    // Mg layout per (wr,wc) tile: [col][rowgrp^((col&15))][4] floats
    // (bank-staggered so fr-lanes spread; write/read use same formula).
    __syncthreads();   // all MFMA reads of sh complete before overwrite
    float* Mg = (float*)sh;            // 64KB needed <= 96KB
    const int mgbase = (wr * 2 + wc) * 4096;
    if (kh) {
#pragma unroll
        for (int mi = 0; mi < 4; ++mi)
#pragma unroll
            for (int ni = 0; ni < 4; ++ni) {
                int col = ni * 16 + fr;
                int adr = mgbase + col * 64 + (((mi * 4 + fq) ^ (col & 15)) << 2);
                *(f32x4*)(Mg + adr) = acc[mi][ni];
            }
    }
    __syncthreads();
    if (!kh) {
        // epilogue: C/D layout col=lane&15, row=(lane>>4)*4+j  [m89-verified]
#pragma unroll
        for (int mi = 0; mi < 4; ++mi) {
#pragma unroll
            for (int ni = 0; ni < 4; ++ni) {
                int col = ni * 16 + fr;
                int adr = mgbase + col * 64 + (((mi * 4 + fq) ^ (col & 15)) << 2);
                f32x4 p = *(const f32x4*)(Mg + adr);
                int gcol = n0 + wc * 64 + col;
                int rowb = m0 + wr * 64 + mi * 16 + fq * 4;
#pragma unroll
                for (int j = 0; j < 4; ++j) {
                    float v = acc[mi][ni][j] + p[j];
                    if (OUT_MODE == 0) {
                        Cb[(size_t)(rowb + j) * N + gcol] = f2b(v);
                    } else {
                        Cf[(size_t)(rowb + j) * N + gcol] = v + bias[gcol];
                    }
                }
            }
        }
    }
}

// ---------------------------------------------------------------------------
// conv: V[m][e] = T[m][e] for e<256 (v0 pass-through);
//       else causal FIR over l with combined taps + boundary corr.
// Thread handles 4 channels x 2 consecutive positions (m even): adjacent
// positions share 12/13 FIR rows -> 14 row-loads per 2 outputs.
// ---------------------------------------------------------------------------
__global__ __launch_bounds__(256) void conv_kernel(
    const unsigned short* __restrict__ T, unsigned short* __restrict__ V,
    const float* __restrict__ H, const float* __restrict__ Beff,
    const float* __restrict__ Corr)
{
    int w  = blockIdx.x * 256 + threadIdx.x;   // 2048*256 work items
    int m  = (w >> 8) * 2;                     // even position; pair never
    int e0 = (w & 255) * 4;                    // crosses batch boundary
    const unsigned short* tp = T + (size_t)m * EDIM + e0;
    unsigned short*       vp = V + (size_t)m * EDIM + e0;
    if (e0 < 256) {                       // v0 pass-through (both rows)
        *(u32x2*)vp = *(const u32x2*)tp;
        *(u32x2*)(vp + EDIM) = *(const u32x2*)(tp + EDIM);
        return;
    }
    int l  = m & (L_SEQ - 1);
    int ch = e0 - 256;
    float4v b4 = *(const float4v*)(Beff + ch);
    float4v acc0 = b4, acc1 = b4;

    // acc1 tap j=0: row m+1
    {
        float4v h = *(const float4v*)(H + ch);      // H[0]
        us4 t = *(const us4*)(tp + EDIM);
        acc1[0] += h[0] * b2f(t[0]); acc1[1] += h[1] * b2f(t[1]);
        acc1[2] += h[2] * b2f(t[2]); acc1[3] += h[3] * b2f(t[3]);
    }
    int ni = (l < 12) ? l : 12;
    for (int i = 0; i <= ni; ++i) {                 // row m-i, taps h[i]/h[i+1]
        us4 t = *(const us4*)(tp - (size_t)i * EDIM);
        float4v h0 = *(const float4v*)(H + i * 768 + ch);
        acc0[0] += h0[0] * b2f(t[0]); acc0[1] += h0[1] * b2f(t[1]);
        acc0[2] += h0[2] * b2f(t[2]); acc0[3] += h0[3] * b2f(t[3]);
        if (i < 12) {
            float4v h1 = *(const float4v*)(H + (i + 1) * 768 + ch);
            acc1[0] += h1[0] * b2f(t[0]); acc1[1] += h1[1] * b2f(t[1]);
            acc1[2] += h1[2] * b2f(t[2]); acc1[3] += h1[3] * b2f(t[3]);
        }
    }
    if (l < 6) {   // bias boundary correction (intermediate zero-padding)
        float4v c = *(const float4v*)(Corr + l * 768 + ch);
        acc0[0] -= c[0]; acc0[1] -= c[1]; acc0[2] -= c[2]; acc0[3] -= c[3];
    }
    if (l + 1 < 6) {
        float4v c = *(const float4v*)(Corr + (l + 1) * 768 + ch);
        acc1[0] -= c[0]; acc1[1] -= c[1]; acc1[2] -= c[2]; acc1[3] -= c[3];
    }
    us4 o0, o1;
    o0[0] = f2b(acc0[0]); o0[1] = f2b(acc0[1]); o0[2] = f2b(acc0[2]); o0[3] = f2b(acc0[3]);
    o1[0] = f2b(acc1[0]); o1[1] = f2b(acc1[1]); o1[2] = f2b(acc1[2]); o1[3] = f2b(acc1[3]);
    *(us4*)vp = o0;
    *(us4*)(vp + EDIM) = o1;
}

// ---------------------------------------------------------------------------
extern "C" void kernel_launch(void* const* d_in, const int* in_sizes, int n_in,
                              void* d_out, int out_size, void* d_ws, size_t ws_size,
                              hipStream_t stream)
{
    const float* x  = (const float*)d_in[0];
    const float* Wq = (const float*)d_in[1];
    // d_in[2] = Wk (dead: attention output is multiplied by 0.0)
    const float* Wv = (const float*)d_in[3];
    const float* Wo = (const float*)d_in[4];
    const float* bo = (const float*)d_in[5];

    uint8_t* ws = (uint8_t*)d_ws;
    unsigned short* xb  = (unsigned short*)(ws);                    //  8 MB
    unsigned short* W1b = (unsigned short*)(ws + (8u  << 20));      //  2 MB
    unsigned short* Wob = (unsigned short*)(ws + (10u << 20));      //  2 MB
    unsigned short* T   = (unsigned short*)(ws + (12u << 20));      //  8 MB
    unsigned short* V   = (unsigned short*)(ws + (20u << 20));      //  8 MB
    float* H    = (float*)(ws + (28u << 20));                        // 40 KB
    float* Beff = (float*)(ws + (28u << 20) + (64u << 10));          //  3 KB
    float* Corr = (float*)(ws + (28u << 20) + (96u << 10));          // 18 KB

    prep_kernel<<<6147, 256, 0, stream>>>(
        x, Wq, Wv, Wo, xb, W1b, Wob,
        (const float*)d_in[6],  (const float*)d_in[7],
        (const float*)d_in[10], (const float*)d_in[11],
        (const float*)d_in[12], (const float*)d_in[13],
        (const float*)d_in[16], (const float*)d_in[17],
        (const float*)d_in[18], (const float*)d_in[19],
        (const float*)d_in[22], (const float*)d_in[23],
        H, Beff, Corr);

    dim3 gg(EDIM / 128, MTOT / 128);   // (8, 32) = 256 blocks, 1 per CU
    gemm_ks<0><<<gg, 512, 0, stream>>>(xb, W1b, T, nullptr, nullptr, MTOT, EDIM, EDIM);

    conv_kernel<<<2048, 256, 0, stream>>>(T, V, H, Beff, Corr);

    gemm_ks<1><<<gg, 512, 0, stream>>>(V, Wob, nullptr, (float*)d_out, bo, MTOT, EDIM, EDIM);
}